// Round 11
// baseline (30622.623 us; speedup 1.0000x reference)
//
#include <hip/hip_runtime.h>
#include <stdint.h>

#define N_B 32
#define T_S 2048
#define H_D 1024
#define NSET 8                       // 8 sets x 32 blocks; set owns 4 batches

typedef unsigned long long u64;
typedef __attribute__((ext_vector_type(4))) unsigned u32x4;

// One DPP f32 add-reduce step: x += dpp(x) on enabled rows.
template<int CTRL, int ROWMASK>
__device__ __forceinline__ float dpp_add(float x) {
    int t = __builtin_amdgcn_update_dpp(0, __builtin_bit_cast(int, x),
                                        CTRL, ROWMASK, 0xf, true);
    return x + __builtin_bit_cast(float, t);
}

// L1-bypass, L2-HIT load of 2 packets (16B). sc0 only: served by the XCD's
// shared L2 (~200cyc), NOT the MALL (~900cyc) like agent-scope atomics.
__device__ __forceinline__ u32x4 ld4_sc0(const u64* p) {
    u32x4 r;
    asm volatile("global_load_dwordx4 %0, %1, off sc0\n\ts_waitcnt vmcnt(0)"
                 : "=&v"(r) : "v"(p) : "memory");
    return r;
}

// Poll one packet pair (rows 2t,2t+1) until both tags match. Fast path spins
// on the XCD L2 (sc0); every 32 spins falls back to MALL (agent atomics) so a
// wrong block->XCD mapping degrades to slow, never to deadlock/stale.
__device__ __forceinline__ void poll_pair(u64* p, unsigned tag,
                                          unsigned& d0, unsigned& d1,
                                          u32x4 r) {
    int spins = 0;
    while (r.y != tag || r.w != tag) {
        if ((++spins & 31) == 0) {
            u64 q0 = __hip_atomic_load(p,     __ATOMIC_RELAXED, __HIP_MEMORY_SCOPE_AGENT);
            u64 q1 = __hip_atomic_load(p + 1, __ATOMIC_RELAXED, __HIP_MEMORY_SCOPE_AGENT);
            r.x = (unsigned)q0; r.y = (unsigned)(q0 >> 32);
            r.z = (unsigned)q1; r.w = (unsigned)(q1 >> 32);
        } else {
            r = ld4_sc0(p);
        }
    }
    d0 = r.x; d1 = r.z;
}

// fast tanh: clamp + v_exp_f32 + v_rcp_f32;  |err| ~1e-6, threshold 1.3e-2
__device__ __forceinline__ float fast_tanh(float x) {
    float xc = fminf(fmaxf(x, -10.0f), 10.0f);
    float e  = __builtin_amdgcn_exp2f(xc * 2.885390081777927f);  // e^{2x}
    return (e - 1.0f) * __builtin_amdgcn_rcpf(e + 1.0f);
}

// Persistent RNN — W in LDS col-major (r8: bank = rc%32, conflict-free);
// two-chain interleave (r10); NEW: XCD-local packet exchange.
//   publish: volatile store (shared XCD L2) + agent store (MALL copy).
//   poll:    sc0 dwordx4 spin on L2; periodic MALL fallback for safety.
// Packets u64 (tag<<32 | f32 bits), [parity][set][chain][batch][row],
// parity double-buffered (overwrite of slot (p,t) happens at t+2, after all
// consumers read tag t — r2 induction). Cross-replay stale packets are
// HARMLESS: inputs are identical each replay, so tag t implies identical
// data bits; initial 0xAA poison never matches tags 1..2047.
__global__ __launch_bounds__(512, 1) void rnn_persist(
    const int* __restrict__ xx, const float* __restrict__ embed,
    const float* __restrict__ W, const float* __restrict__ bh,
    float* __restrict__ out, u64* __restrict__ ws)
{
    __shared__ float  wlds[32 * 1024];   // W slice, col-major, 128 KB
    __shared__ float2 h2A[1024];         // chain A h: {b0,b1} per row
    __shared__ float2 h2B[1024];         // chain B h: {b2,b3} per row
    __shared__ float  xhA[2][32];        // embed slice, chain A, current step
    __shared__ float  xhB[2][32];

    const int tid = threadIdx.x;
    const int blk = blockIdx.x;
    const int g  = blk & 7;              // set id == XCD id (round-robin)
    const int s  = blk >> 3;             // col slice 0..31
    const int n0 = g * 4;                // set's first batch
    const int wv = tid >> 6;             // wave id: 4-col chunk
    const int rc = tid & 63;             // lane
    const int c_base = s * 32 + wv * 4;

    // ---- one-time: stage W slice into LDS, col-major (proven r8) ----
    {
        int r0 = tid >> 3, c4 = tid & 7;
        for (int i = 0; i < 16; ++i) {
            int row = r0 + i * 64;
            float4 v = *(const float4*)(W + (size_t)row * H_D + s * 32 + c4 * 4);
            wlds[(c4 * 4 + 0) * 1024 + row] = v.x;
            wlds[(c4 * 4 + 1) * 1024 + row] = v.y;
            wlds[(c4 * 4 + 2) * 1024 + row] = v.z;
            wlds[(c4 * 4 + 3) * 1024 + row] = v.w;
        }
    }
    for (int e = tid; e < 1024; e += 512) {
        h2A[e] = float2{0.0f, 0.0f};     // h_0 = 0
        h2B[e] = float2{0.0f, 0.0f};
    }

    // ---- embed pre-stage: xh for step 1 direct; prefetch step 2 ----
    const int eb = tid >> 5, ec = tid & 31;   // batch-in-set, col (tid<128)
    float r_xh = 0.0f;
    int   r_tok = 0;
    if (tid < 128) {
        const size_t nn = (size_t)(n0 + eb) * T_S;
        int tk0 = xx[nn + 0];
        float v0 = embed[(size_t)tk0 * H_D + s * 32 + ec];
        if (eb < 2) xhA[eb][ec] = v0; else xhB[eb - 2][ec] = v0;
        int tk1 = xx[nn + 1];
        r_xh  = embed[(size_t)tk1 * H_D + s * 32 + ec];
        r_tok = xx[nn + 2];
    }
    __syncthreads();

    // lanes 56..63 of each wave own its 8 outputs (2 batches x 4 cols)/chain
    const int o = rc - 56;
    int my_c = 0, xh_i = 0; float biasv = 0.0f;
    if (o >= 0) {
        const int oj = o & 3;
        my_c  = c_base + oj;
        biasv = bh[my_c];
        xh_i  = ((o >> 2) & 1) * 32 + (wv * 4 + oj);
    }
    const int ob = (o >= 0) ? ((o >> 2) & 1) : 0;

    const float* wbase = &wlds[(wv * 4) * 1024 + rc];
    // packet indexing: [parity][set][chain][batch-in-chain][row]
#define PKT(P, CH, B, ROW) (ws + ((((size_t)(P) * NSET + g) * 2 + (CH)) * 2 + (B)) * 1024 + (ROW))

    for (int t = 1; t <= T_S; ++t) {
        const int p = t & 1;

        // ================= P1 + P2: compute & publish both chains ==========
#pragma unroll
        for (int ch = 0; ch < 2; ++ch) {
            const float2* hb = ch ? &h2B[rc] : &h2A[rc];
            float acc[2][4];
#pragma unroll
            for (int b = 0; b < 2; ++b)
#pragma unroll
                for (int j = 0; j < 4; ++j) acc[b][j] = 0.0f;
#pragma unroll
            for (int k = 0; k < 16; ++k) {
                float2 a  = hb[k * 64];
                float w0 = wbase[k * 64];
                float w1 = wbase[k * 64 + 1024];
                float w2 = wbase[k * 64 + 2048];
                float w3 = wbase[k * 64 + 3072];
                acc[0][0] = fmaf(a.x, w0, acc[0][0]);
                acc[0][1] = fmaf(a.x, w1, acc[0][1]);
                acc[0][2] = fmaf(a.x, w2, acc[0][2]);
                acc[0][3] = fmaf(a.x, w3, acc[0][3]);
                acc[1][0] = fmaf(a.y, w0, acc[1][0]);
                acc[1][1] = fmaf(a.y, w1, acc[1][1]);
                acc[1][2] = fmaf(a.y, w2, acc[1][2]);
                acc[1][3] = fmaf(a.y, w3, acc[1][3]);
            }
            // 64-lane reduce of 8 values; totals land in lanes 48..63 row 3
            float outv = 0.0f;
#pragma unroll
            for (int oo = 0; oo < 8; ++oo) {
                float v = acc[oo >> 2][oo & 3];
                v = dpp_add<0xB1,  0xf>(v);   // quad_perm xor1
                v = dpp_add<0x4E,  0xf>(v);   // quad_perm xor2
                v = dpp_add<0x141, 0xf>(v);   // row_half_mirror
                v = dpp_add<0x140, 0xf>(v);   // row_mirror
                v = dpp_add<0x142, 0xa>(v);   // row_bcast15
                v = dpp_add<0x143, 0xc>(v);   // row_bcast31 -> total
                if (o == oo) outv = v;
            }
            if (o >= 0) {
                const float* xh = ch ? (const float*)xhB : (const float*)xhA;
                float pre = outv + xh[xh_i] + biasv;
                float hv  = fast_tanh(pre);
                u64 pk = ((u64)(unsigned)t << 32)
                       | (u64)__builtin_bit_cast(unsigned, hv);
                u64* pp = PKT(p, ch, ob, my_c);
                *(volatile u64*)pp = pk;   // fast path: shared XCD L2
                __hip_atomic_store(pp, pk, __ATOMIC_RELAXED,
                                   __HIP_MEMORY_SCOPE_AGENT);  // MALL copy
                const int n = n0 + ch * 2 + ob;
                out[((size_t)n * T_S + (t - 1)) * H_D + my_c] = hv;
                if (t == T_S)
                    out[(size_t)N_B * T_S * H_D + (size_t)n * H_D + my_c] = hv;
            }
        }
        __syncthreads();   // BAR1: all GEMV/xh reads of step t complete

        // ============ P3 + P4: fetch h_t (tag=t) for step t+1 ==============
        if (t < T_S) {
            const unsigned tag = (unsigned)t;
            const int r2 = 2 * tid;        // this thread: rows r2, r2+1
            u64* pA0 = PKT(p, 0, 0, r2);
            u64* pA1 = PKT(p, 0, 1, r2);
            u64* pB0 = PKT(p, 1, 0, r2);
            u64* pB1 = PKT(p, 1, 1, r2);

            // xh staging for step t+1 FIRST (its global loads drain with the
            // packet vmcnt anyway; issue early)
            if (tid < 128) {
                if (eb < 2) xhA[eb][ec] = r_xh; else xhB[eb - 2][ec] = r_xh;
                int ti = t + 2 < T_S ? t + 2 : T_S - 1;
                r_xh  = embed[(size_t)r_tok * H_D + s * 32 + ec];
                r_tok = xx[(size_t)(n0 + eb) * T_S + ti];
            }

            // issue all 4 pair-loads up front (pipelined L2 latency)
            u32x4 rA0, rA1, rB0, rB1;
            asm volatile(
                "global_load_dwordx4 %0, %4, off sc0\n\t"
                "global_load_dwordx4 %1, %5, off sc0\n\t"
                "global_load_dwordx4 %2, %6, off sc0\n\t"
                "global_load_dwordx4 %3, %7, off sc0\n\t"
                "s_waitcnt vmcnt(0)"
                : "=&v"(rA0), "=&v"(rA1), "=&v"(rB0), "=&v"(rB1)
                : "v"(pA0), "v"(pA1), "v"(pB0), "v"(pB1)
                : "memory");

            unsigned a00, a01, a10, a11, b00, b01, b10, b11;
            poll_pair(pA0, tag, a00, a01, rA0);
            poll_pair(pA1, tag, a10, a11, rA1);
            h2A[r2]     = float2{ __builtin_bit_cast(float, a00),
                                  __builtin_bit_cast(float, a10) };
            h2A[r2 + 1] = float2{ __builtin_bit_cast(float, a01),
                                  __builtin_bit_cast(float, a11) };
            poll_pair(pB0, tag, b00, b01, rB0);
            poll_pair(pB1, tag, b10, b11, rB1);
            h2B[r2]     = float2{ __builtin_bit_cast(float, b00),
                                  __builtin_bit_cast(float, b10) };
            h2B[r2 + 1] = float2{ __builtin_bit_cast(float, b01),
                                  __builtin_bit_cast(float, b11) };
        }
        __syncthreads();   // BAR2: new h/xh visible before next step
    }
#undef PKT
}

extern "C" void kernel_launch(void* const* d_in, const int* in_sizes, int n_in,
                              void* d_out, int out_size, void* d_ws, size_t ws_size,
                              hipStream_t stream) {
    const int*   xx    = (const int*)d_in[0];
    const float* embed = (const float*)d_in[1];
    const float* W     = (const float*)d_in[2];
    const float* bh    = (const float*)d_in[3];
    float* out = (float*)d_out;
    u64*   ws  = (u64*)d_ws;

    // clear packet tags each call (2*8*2*2*1024 u64 = 512 KB)
    hipMemsetAsync(d_ws, 0, (size_t)2 * NSET * 2 * 2 * 1024 * sizeof(u64), stream);

    void* args[] = { (void*)&xx, (void*)&embed, (void*)&W, (void*)&bh,
                     (void*)&out, (void*)&ws };
    hipLaunchCooperativeKernel((const void*)rnn_persist, dim3(256), dim3(512),
                               args, 0, stream);
}

// Round 12
// 7138.024 us; speedup vs baseline: 4.2901x; 4.2901x over previous
//
#include <hip/hip_runtime.h>
#include <stdint.h>

#define N_B 32
#define T_S 2048
#define H_D 1024
#define NSET 8                       // 8 sets x 32 blocks; set owns 4 batches

typedef unsigned long long u64;

// One DPP f32 add-reduce step: x += dpp(x) on enabled rows.
template<int CTRL, int ROWMASK>
__device__ __forceinline__ float dpp_add(float x) {
    int t = __builtin_amdgcn_update_dpp(0, __builtin_bit_cast(int, x),
                                        CTRL, ROWMASK, 0xf, true);
    return x + __builtin_bit_cast(float, t);
}

// Spin until packet tag matches `want` (tagged data: the load IS the poll,
// so data latency self-hides). Periodic RMW = livelock insurance only.
__device__ __forceinline__ u64 wait_pkt(u64* a, unsigned want, u64 v) {
    int spins = 0;
    while ((unsigned)(v >> 32) != want) {
        if ((++spins & 63) == 0)
            v = __hip_atomic_fetch_or(a, 0ull, __ATOMIC_RELAXED, __HIP_MEMORY_SCOPE_AGENT);
        else
            v = __hip_atomic_load(a, __ATOMIC_RELAXED, __HIP_MEMORY_SCOPE_AGENT);
    }
    return v;
}

// fast tanh: clamp + v_exp_f32 + v_rcp_f32;  |err| ~1e-6, threshold 1.3e-2
__device__ __forceinline__ float fast_tanh(float x) {
    float xc = fminf(fmaxf(x, -10.0f), 10.0f);
    float e  = __builtin_amdgcn_exp2f(xc * 2.885390081777927f);  // e^{2x}
    return (e - 1.0f) * __builtin_amdgcn_rcpf(e + 1.0f);
}

// LDS-only barrier: s_waitcnt lgkmcnt(0) + s_barrier, NO vmcnt(0) drain.
// __syncthreads() would drain all in-flight HBM stores (z-writes, packets)
// and the embed prefetch at EVERY barrier (~1us/step of useless stall).
// Correctness without vmcnt drain:
//  - packet exchange is self-validating (tag check); r2 induction proves a
//    producer reaches publish(t+2,slot p) only after all blocks READ tag t
//    from slot p (through data dependence), so no overwrite race.
//  - z-stores are fire-and-forget; embed loads get compiler waitcnt at use.
// rule-18: sched_barrier(0) fences keep the compiler from hoisting LDS ops
// across the inline-asm waitcnt.
__device__ __forceinline__ void bar_lds() {
    __builtin_amdgcn_sched_barrier(0);
    asm volatile("s_waitcnt lgkmcnt(0)" ::: "memory");
    __builtin_amdgcn_sched_barrier(0);
    __builtin_amdgcn_s_barrier();
    __builtin_amdgcn_sched_barrier(0);
}

// Persistent RNN — W in LDS col-major (r8: bank = rc%32, 2 lanes/bank, free);
// two-chain interleave (r10: each chain's publish->poll RTT partially hides
// behind the other chain's compute); tagged-packet exchange at agent scope
// (r2-r10 proven); NEW vs r10: LDS-only barriers (no vmcnt drains).
__global__ __launch_bounds__(512, 1) void rnn_persist(
    const int* __restrict__ xx, const float* __restrict__ embed,
    const float* __restrict__ W, const float* __restrict__ bh,
    float* __restrict__ out, u64* __restrict__ ws)
{
    __shared__ float  wlds[32 * 1024];   // W slice, col-major, 128 KB
    __shared__ float2 h2A[1024];         // chain A h: {b0,b1} per row
    __shared__ float2 h2B[1024];         // chain B h: {b2,b3} per row
    __shared__ float  xhA[2][32];        // embed slice, chain A, current step
    __shared__ float  xhB[2][32];

    const int tid = threadIdx.x;
    const int blk = blockIdx.x;
    const int g  = blk & 7;              // set id
    const int s  = blk >> 3;             // col slice 0..31
    const int n0 = g * 4;                // set's first batch
    const int wv = tid >> 6;             // wave id: 4-col chunk
    const int rc = tid & 63;             // lane
    const int c_base = s * 32 + wv * 4;

    // ---- one-time: stage W slice into LDS, col-major (proven r8) ----
    {
        int r0 = tid >> 3, c4 = tid & 7;
        for (int i = 0; i < 16; ++i) {
            int row = r0 + i * 64;
            float4 v = *(const float4*)(W + (size_t)row * H_D + s * 32 + c4 * 4);
            wlds[(c4 * 4 + 0) * 1024 + row] = v.x;
            wlds[(c4 * 4 + 1) * 1024 + row] = v.y;
            wlds[(c4 * 4 + 2) * 1024 + row] = v.z;
            wlds[(c4 * 4 + 3) * 1024 + row] = v.w;
        }
    }
    for (int e = tid; e < 1024; e += 512) {
        h2A[e] = float2{0.0f, 0.0f};     // h_0 = 0
        h2B[e] = float2{0.0f, 0.0f};
    }

    // ---- embed pre-stage: xh for step 1 direct; prefetch step 2 ----
    const int eb = tid >> 5, ec = tid & 31;   // batch-in-set, col (tid<128)
    float r_xh = 0.0f;
    int   r_tok = 0;
    if (tid < 128) {
        const size_t nn = (size_t)(n0 + eb) * T_S;
        int tk0 = xx[nn + 0];
        float v0 = embed[(size_t)tk0 * H_D + s * 32 + ec];
        if (eb < 2) xhA[eb][ec] = v0; else xhB[eb - 2][ec] = v0;
        int tk1 = xx[nn + 1];
        r_xh  = embed[(size_t)tk1 * H_D + s * 32 + ec];
        r_tok = xx[nn + 2];
    }
    __syncthreads();   // one-time full barrier (W staging used global loads)

    // lanes 56..63 of each wave own its 8 outputs (2 batches x 4 cols)/chain
    const int o = rc - 56;
    int my_c = 0, xh_i = 0; float biasv = 0.0f;
    if (o >= 0) {
        const int oj = o & 3;
        my_c  = c_base + oj;
        biasv = bh[my_c];
        xh_i  = ((o >> 2) & 1) * 32 + (wv * 4 + oj);
    }
    const int ob = (o >= 0) ? ((o >> 2) & 1) : 0;

    const float* wbase = &wlds[(wv * 4) * 1024 + rc];
    // packet indexing: [parity][set][chain][batch-in-chain][row]
#define PKT(P, CH, B, ROW) (ws + ((((size_t)(P) * NSET + g) * 2 + (CH)) * 2 + (B)) * 1024 + (ROW))

    for (int t = 1; t <= T_S; ++t) {
        const int p = t & 1;

        // ================= P1 + P2: compute & publish both chains ==========
#pragma unroll
        for (int ch = 0; ch < 2; ++ch) {
            const float2* hb = ch ? &h2B[rc] : &h2A[rc];
            float acc[2][4];
#pragma unroll
            for (int b = 0; b < 2; ++b)
#pragma unroll
                for (int j = 0; j < 4; ++j) acc[b][j] = 0.0f;
#pragma unroll
            for (int k = 0; k < 16; ++k) {
                float2 a  = hb[k * 64];
                float w0 = wbase[k * 64];
                float w1 = wbase[k * 64 + 1024];
                float w2 = wbase[k * 64 + 2048];
                float w3 = wbase[k * 64 + 3072];
                acc[0][0] = fmaf(a.x, w0, acc[0][0]);
                acc[0][1] = fmaf(a.x, w1, acc[0][1]);
                acc[0][2] = fmaf(a.x, w2, acc[0][2]);
                acc[0][3] = fmaf(a.x, w3, acc[0][3]);
                acc[1][0] = fmaf(a.y, w0, acc[1][0]);
                acc[1][1] = fmaf(a.y, w1, acc[1][1]);
                acc[1][2] = fmaf(a.y, w2, acc[1][2]);
                acc[1][3] = fmaf(a.y, w3, acc[1][3]);
            }
            // 64-lane reduce of 8 values; totals land in lanes 48..63 row 3
            float outv = 0.0f;
#pragma unroll
            for (int oo = 0; oo < 8; ++oo) {
                float v = acc[oo >> 2][oo & 3];
                v = dpp_add<0xB1,  0xf>(v);   // quad_perm xor1
                v = dpp_add<0x4E,  0xf>(v);   // quad_perm xor2
                v = dpp_add<0x141, 0xf>(v);   // row_half_mirror
                v = dpp_add<0x140, 0xf>(v);   // row_mirror
                v = dpp_add<0x142, 0xa>(v);   // row_bcast15
                v = dpp_add<0x143, 0xc>(v);   // row_bcast31 -> total
                if (o == oo) outv = v;
            }
            if (o >= 0) {
                const float* xh = ch ? (const float*)xhB : (const float*)xhA;
                float pre = outv + xh[xh_i] + biasv;
                float hv  = fast_tanh(pre);
                // publish FIRST (consumer-visible store leads the chain)
                u64 pk = ((u64)(unsigned)t << 32)
                       | (u64)__builtin_bit_cast(unsigned, hv);
                __hip_atomic_store(PKT(p, ch, ob, my_c), pk,
                                   __ATOMIC_RELAXED, __HIP_MEMORY_SCOPE_AGENT);
                const int n = n0 + ch * 2 + ob;
                out[((size_t)n * T_S + (t - 1)) * H_D + my_c] = hv;
                if (t == T_S)
                    out[(size_t)N_B * T_S * H_D + (size_t)n * H_D + my_c] = hv;
            }
        }
        bar_lds();   // BAR1: LDS-only — all GEMV/xh ds_reads of step t done

        // ============ P3 + P4: fetch h_t (tag=t) for step t+1 ==============
        if (t < T_S) {
            const unsigned tag = (unsigned)t;
            u64 *aA0 = PKT(p, 0, 0, tid),       *aA1 = PKT(p, 0, 1, tid);
            u64 *aA2 = PKT(p, 0, 0, tid + 512), *aA3 = PKT(p, 0, 1, tid + 512);
            u64 *aB0 = PKT(p, 1, 0, tid),       *aB1 = PKT(p, 1, 1, tid);
            u64 *aB2 = PKT(p, 1, 0, tid + 512), *aB3 = PKT(p, 1, 1, tid + 512);
            // issue all 8 loads up front (pipelined MALL latency)
            u64 vA0 = __hip_atomic_load(aA0, __ATOMIC_RELAXED, __HIP_MEMORY_SCOPE_AGENT);
            u64 vA1 = __hip_atomic_load(aA1, __ATOMIC_RELAXED, __HIP_MEMORY_SCOPE_AGENT);
            u64 vA2 = __hip_atomic_load(aA2, __ATOMIC_RELAXED, __HIP_MEMORY_SCOPE_AGENT);
            u64 vA3 = __hip_atomic_load(aA3, __ATOMIC_RELAXED, __HIP_MEMORY_SCOPE_AGENT);
            u64 vB0 = __hip_atomic_load(aB0, __ATOMIC_RELAXED, __HIP_MEMORY_SCOPE_AGENT);
            u64 vB1 = __hip_atomic_load(aB1, __ATOMIC_RELAXED, __HIP_MEMORY_SCOPE_AGENT);
            u64 vB2 = __hip_atomic_load(aB2, __ATOMIC_RELAXED, __HIP_MEMORY_SCOPE_AGENT);
            u64 vB3 = __hip_atomic_load(aB3, __ATOMIC_RELAXED, __HIP_MEMORY_SCOPE_AGENT);

            // xh staging for step t+1 (overlaps the packet waits)
            if (tid < 128) {
                if (eb < 2) xhA[eb][ec] = r_xh; else xhB[eb - 2][ec] = r_xh;
                int ti = t + 2 < T_S ? t + 2 : T_S - 1;
                r_xh  = embed[(size_t)r_tok * H_D + s * 32 + ec];
                r_tok = xx[(size_t)(n0 + eb) * T_S + ti];
            }

            vA0 = wait_pkt(aA0, tag, vA0);
            vA1 = wait_pkt(aA1, tag, vA1);
            vA2 = wait_pkt(aA2, tag, vA2);
            vA3 = wait_pkt(aA3, tag, vA3);
            h2A[tid]       = float2{ __builtin_bit_cast(float, (unsigned)vA0),
                                     __builtin_bit_cast(float, (unsigned)vA1) };
            h2A[tid + 512] = float2{ __builtin_bit_cast(float, (unsigned)vA2),
                                     __builtin_bit_cast(float, (unsigned)vA3) };
            vB0 = wait_pkt(aB0, tag, vB0);
            vB1 = wait_pkt(aB1, tag, vB1);
            vB2 = wait_pkt(aB2, tag, vB2);
            vB3 = wait_pkt(aB3, tag, vB3);
            h2B[tid]       = float2{ __builtin_bit_cast(float, (unsigned)vB0),
                                     __builtin_bit_cast(float, (unsigned)vB1) };
            h2B[tid + 512] = float2{ __builtin_bit_cast(float, (unsigned)vB2),
                                     __builtin_bit_cast(float, (unsigned)vB3) };
        }
        bar_lds();   // BAR2: LDS-only — new h/xh visible before next step
    }
#undef PKT
}

extern "C" void kernel_launch(void* const* d_in, const int* in_sizes, int n_in,
                              void* d_out, int out_size, void* d_ws, size_t ws_size,
                              hipStream_t stream) {
    const int*   xx    = (const int*)d_in[0];
    const float* embed = (const float*)d_in[1];
    const float* W     = (const float*)d_in[2];
    const float* bh    = (const float*)d_in[3];
    float* out = (float*)d_out;
    u64*   ws  = (u64*)d_ws;

    // clear packet tags each call (2*8*2*2*1024 u64 = 512 KB)
    hipMemsetAsync(d_ws, 0, (size_t)2 * NSET * 2 * 2 * 1024 * sizeof(u64), stream);

    void* args[] = { (void*)&xx, (void*)&embed, (void*)&W, (void*)&bh,
                     (void*)&out, (void*)&ws };
    hipLaunchCooperativeKernel((const void*)rnn_persist, dim3(256), dim3(512),
                               args, 0, stream);
}